// Round 2
// baseline (1126.931 us; speedup 1.0000x reference)
//
#include <hip/hip_runtime.h>

#define N_NODES 100000
#define N_EDGES 3200000
#define QCH 32
#define DT_C 0.1f

// ============================ CSR-gather path ============================
// ws layout:
//   int2 recs[2E]            (51,200,000 B)
//   int  odeg[N]             (400,000 B)
//   int  cnt[N]              (400,000 B)
//   int  off[N]              (400,000 B)
//   int  cur[N]              (400,000 B)
//   int  part[128]           (512 B)

__global__ void count_kernel(const int* __restrict__ src,
                             const int* __restrict__ dst,
                             int* __restrict__ odeg,
                             int* __restrict__ cnt, int E) {
    int e = blockIdx.x * blockDim.x + threadIdx.x;
    if (e < E) {
        int s = src[e], d = dst[e];
        atomicAdd(&odeg[s], 1);
        atomicAdd(&cnt[s], 1);
        atomicAdd(&cnt[d], 1);
    }
}

// exclusive scan, stage 1: per-1024-block scan + block totals
__global__ void scan1_kernel(const int* __restrict__ cnt,
                             int* __restrict__ off,
                             int* __restrict__ part, int n) {
    __shared__ int sh[1024];
    int i = blockIdx.x * 1024 + threadIdx.x;
    int v = (i < n) ? cnt[i] : 0;
    sh[threadIdx.x] = v;
    __syncthreads();
    for (int o = 1; o < 1024; o <<= 1) {
        int t = (threadIdx.x >= o) ? sh[threadIdx.x - o] : 0;
        __syncthreads();
        sh[threadIdx.x] += t;
        __syncthreads();
    }
    if (i < n) off[i] = sh[threadIdx.x] - v;          // exclusive
    if (threadIdx.x == 1023) part[blockIdx.x] = sh[1023];
}

// stage 2: exclusive scan of the (<=128) block totals, in place
__global__ void scan2_kernel(int* __restrict__ part, int nb) {
    __shared__ int sh[128];
    int v = (threadIdx.x < nb) ? part[threadIdx.x] : 0;
    sh[threadIdx.x] = v;
    __syncthreads();
    for (int o = 1; o < 128; o <<= 1) {
        int t = (threadIdx.x >= o) ? sh[threadIdx.x - o] : 0;
        __syncthreads();
        sh[threadIdx.x] += t;
        __syncthreads();
    }
    if (threadIdx.x < nb) part[threadIdx.x] = sh[threadIdx.x] - v;
}

// stage 3: add block offsets; also init cursor array
__global__ void scan3_kernel(int* __restrict__ off,
                             int* __restrict__ cur,
                             const int* __restrict__ part, int n) {
    int i = blockIdx.x * 1024 + threadIdx.x;
    if (i < n) {
        int o = off[i] + part[blockIdx.x];
        off[i] = o;
        cur[i] = o;
    }
}

// fill incidence records: each edge contributes (dst,c) at src and (src,c) at dst
__global__ void fill_kernel(const int* __restrict__ src,
                            const int* __restrict__ dst,
                            const float* __restrict__ w,
                            const int* __restrict__ odeg,
                            int* __restrict__ cur,
                            int2* __restrict__ recs, int E) {
    int e = blockIdx.x * blockDim.x + threadIdx.x;
    if (e >= E) return;
    int s = src[e], d = dst[e];
    float c = w[e] / fmaxf((float)odeg[s], 1.0f);
    int ci = __float_as_int(c);
    int p1 = atomicAdd(&cur[s], 1);
    recs[p1] = make_int2(d, ci);
    int p2 = atomicAdd(&cur[d], 1);
    recs[p2] = make_int2(s, ci);
}

// one wave per node: lanes split into 2 half-groups of 32 (q = lane&31),
// alternating incidence records; fused finalize.
__global__ __launch_bounds__(256) void gather_kernel(
        const float* __restrict__ f,
        const float* __restrict__ coll,
        const float* __restrict__ srct,
        const int* __restrict__ off,
        const int2* __restrict__ recs,
        float* __restrict__ out, int n) {
    int wid = (int)((blockIdx.x * (unsigned)blockDim.x + threadIdx.x) >> 6);
    if (wid >= n) return;
    int lane = threadIdx.x & 63;
    int q = lane & 31;
    int half = lane >> 5;

    int beg = off[wid];
    int end = (wid == n - 1) ? (2 * N_EDGES) : off[wid + 1];

    int idx = wid * QCH + q;
    float fn = fmaxf(f[idx], 0.0f);
    float facc = 0.0f, csum = 0.0f;

    for (int i = beg + half; i < end; i += 2) {
        int2 r = recs[i];
        float c = __int_as_float(r.y);
        facc = fmaf(c, fmaxf(f[r.x * QCH + q], 0.0f), facc);
        csum += c;
    }
    // combine the two half-groups across the 64-lane wave
    facc += __shfl_xor(facc, 32);
    csum += __shfl_xor(csum, 32);

    if (half == 0) {
        float xi = (75.0f / 31.0f) * (float)q;
        float tr = xi * (facc - fn * csum);
        out[idx] = fmaxf(fn - DT_C * (tr - coll[idx] - srct[idx]), 0.0f);
    }
}

// ============================ fallback (atomic) path ============================

__global__ void deg_kernel(const int* __restrict__ src,
                           float* __restrict__ deg, int E) {
    int e = blockIdx.x * blockDim.x + threadIdx.x;
    if (e < E) atomicAdd(&deg[src[e]], 1.0f);
}

__global__ void edge_kernel(const float* __restrict__ f,
                            const float* __restrict__ w,
                            const int* __restrict__ src,
                            const int* __restrict__ dst,
                            const float* __restrict__ deg,
                            float* __restrict__ trans, int E) {
    long long t = (long long)blockIdx.x * blockDim.x + threadIdx.x;
    int e = (int)(t >> 5);
    int q = (int)(t & 31);
    if (e >= E) return;
    int s = src[e];
    int d = dst[e];
    float coef = w[e] / fmaxf(deg[s], 1.0f);
    float xi = (75.0f / 31.0f) * (float)q;
    float fs = fmaxf(f[s * QCH + q], 0.0f);
    float fd = fmaxf(f[d * QCH + q], 0.0f);
    float msg = coef * xi * (fd - fs);
    atomicAdd(&trans[s * QCH + q],  msg);
    atomicAdd(&trans[d * QCH + q], -msg);
}

__global__ void final_kernel(const float* __restrict__ fdist,
                             const float* __restrict__ coll,
                             const float* __restrict__ srct,
                             float* __restrict__ out, int n) {
    int i = blockIdx.x * blockDim.x + threadIdx.x;
    if (i < n) {
        float fr = fmaxf(fdist[i], 0.0f);
        float t = out[i];
        out[i] = fmaxf(fr - DT_C * (t - coll[i] - srct[i]), 0.0f);
    }
}

// ============================ launch ============================

extern "C" void kernel_launch(void* const* d_in, const int* in_sizes, int n_in,
                              void* d_out, int out_size, void* d_ws, size_t ws_size,
                              hipStream_t stream) {
    const float* f    = (const float*)d_in[0];
    const float* coll = (const float*)d_in[1];
    const float* srct = (const float*)d_in[2];
    const float* w    = (const float*)d_in[3];
    const int*   src  = (const int*)d_in[4];
    const int*   dst  = (const int*)d_in[5];
    float* out = (float*)d_out;

    const int N = N_NODES;
    const int E = N_EDGES;

    const size_t REC_BYTES = (size_t)2 * E * sizeof(int2);    // 51.2 MB
    const size_t NEEDED = REC_BYTES + (size_t)4 * N * sizeof(int) + 512;

    if (ws_size >= NEEDED) {
        int2* recs = (int2*)d_ws;
        int* odeg = (int*)((char*)d_ws + REC_BYTES);
        int* cnt  = odeg + N;
        int* off  = cnt + N;
        int* cur  = off + N;
        int* part = cur + N;

        // zero odeg + cnt (contiguous)
        hipMemsetAsync(odeg, 0, (size_t)2 * N * sizeof(int), stream);

        count_kernel<<<(E + 255) / 256, 256, 0, stream>>>(src, dst, odeg, cnt, E);

        int nb = (N + 1023) / 1024;   // 98
        scan1_kernel<<<nb, 1024, 0, stream>>>(cnt, off, part, N);
        scan2_kernel<<<1, 128, 0, stream>>>(part, nb);
        scan3_kernel<<<nb, 1024, 0, stream>>>(off, cur, part, N);

        fill_kernel<<<(E + 255) / 256, 256, 0, stream>>>(src, dst, w, odeg, cur, recs, E);

        int waves_per_block = 256 / 64;
        int blocks = (N + waves_per_block - 1) / waves_per_block;
        gather_kernel<<<blocks, 256, 0, stream>>>(f, coll, srct, off, recs, out, N);
    } else {
        // fallback: proven atomic-scatter path
        float* deg = (float*)d_ws;
        hipMemsetAsync(deg, 0, N * sizeof(float), stream);
        hipMemsetAsync(out, 0, (size_t)N * QCH * sizeof(float), stream);
        deg_kernel<<<(E + 255) / 256, 256, 0, stream>>>(src, deg, E);
        long long total = (long long)E * QCH;
        int blocks = (int)((total + 255) / 256);
        edge_kernel<<<blocks, 256, 0, stream>>>(f, w, src, dst, deg, out, E);
        int n = N * QCH;
        final_kernel<<<(n + 255) / 256, 256, 0, stream>>>(f, coll, srct, out, n);
    }
}

// Round 3
// 496.346 us; speedup vs baseline: 2.2705x; 2.2705x over previous
//
#include <hip/hip_runtime.h>
#include <hip/hip_fp16.h>

#define N_NODES 100000
#define N_EDGES 3200000
#define QCH 32
#define QP (QCH / 2)          // 16 half2 pairs per node
#define DT_C 0.1f

// Kernel 1: out-degree of each node (float, matches segment_sum of ones)
__global__ void deg_kernel(const int* __restrict__ src,
                           float* __restrict__ deg, int E) {
    int e = blockIdx.x * blockDim.x + threadIdx.x;
    if (e < E) atomicAdd(&deg[src[e]], 1.0f);
}

// Kernel 2: one thread per (edge, q-pair). Two messages packed into one
// half2 atomic per endpoint -> half the atomic ops / bytes of the fp32 path.
__global__ void edge_kernel_h2(const float2* __restrict__ f2,
                               const float* __restrict__ w,
                               const int* __restrict__ src,
                               const int* __restrict__ dst,
                               const float* __restrict__ deg,
                               __half2* __restrict__ trans, int E) {
    long long t = (long long)blockIdx.x * blockDim.x + threadIdx.x;
    int e = (int)(t >> 4);
    int qp = (int)(t & 15);
    if (e >= E) return;
    int s = src[e];
    int d = dst[e];
    float coef = w[e] / fmaxf(deg[s], 1.0f);
    float2 fs = f2[s * QP + qp];
    float2 fd = f2[d * QP + qp];
    float xi0 = (75.0f / 31.0f) * (float)(2 * qp);
    float xi1 = (75.0f / 31.0f) * (float)(2 * qp + 1);
    float m0 = coef * xi0 * (fmaxf(fd.x, 0.0f) - fmaxf(fs.x, 0.0f));
    float m1 = coef * xi1 * (fmaxf(fd.y, 0.0f) - fmaxf(fs.y, 0.0f));
    __half2 mp = __floats2half2_rn(m0, m1);
    __half2 mn = __floats2half2_rn(-m0, -m1);
    unsafeAtomicAdd(&trans[s * QP + qp], mp);   // outflow at src
    unsafeAtomicAdd(&trans[d * QP + qp], mn);   // -inflow at dst
}

// Kernel 3: finalize, one thread per q-pair, float2 output writes.
__global__ void final_h2(const float2* __restrict__ fdist,
                         const float2* __restrict__ coll,
                         const float2* __restrict__ srct,
                         const __half2* __restrict__ trans,
                         float2* __restrict__ out, int n2) {
    int i = blockIdx.x * blockDim.x + threadIdx.x;
    if (i >= n2) return;
    float2 tv = __half22float2(trans[i]);
    float2 fr = fdist[i];
    float2 cl = coll[i];
    float2 st = srct[i];
    float f0 = fmaxf(fr.x, 0.0f);
    float f1 = fmaxf(fr.y, 0.0f);
    float2 o;
    o.x = fmaxf(f0 - DT_C * (tv.x - cl.x - st.x), 0.0f);
    o.y = fmaxf(f1 - DT_C * (tv.y - cl.y - st.y), 0.0f);
    out[i] = o;
}

extern "C" void kernel_launch(void* const* d_in, const int* in_sizes, int n_in,
                              void* d_out, int out_size, void* d_ws, size_t ws_size,
                              hipStream_t stream) {
    const float* f    = (const float*)d_in[0];  // [N, Q]
    const float* coll = (const float*)d_in[1];  // [N, Q]
    const float* srct = (const float*)d_in[2];  // [N, Q]
    const float* w    = (const float*)d_in[3];  // [E]
    const int*   src  = (const int*)d_in[4];    // [E]
    const int*   dst  = (const int*)d_in[5];    // [E]
    float* out = (float*)d_out;                 // [N, Q]

    const int N = N_NODES;
    const int E = N_EDGES;

    // ws layout: half2 trans[N*QP] (6.4 MB), then float deg[N] (400 KB)
    __half2* trans = (__half2*)d_ws;
    float* deg = (float*)((char*)d_ws + (size_t)N * QP * sizeof(__half2));

    hipMemsetAsync(trans, 0, (size_t)N * QP * sizeof(__half2), stream);  // 0 bits == 0.0h
    hipMemsetAsync(deg, 0, (size_t)N * sizeof(float), stream);

    deg_kernel<<<(E + 255) / 256, 256, 0, stream>>>(src, deg, E);

    long long total = (long long)E * QP;
    int blocks = (int)((total + 255) / 256);
    edge_kernel_h2<<<blocks, 256, 0, stream>>>((const float2*)f, w, src, dst,
                                               deg, trans, E);

    int n2 = N * QP;
    final_h2<<<(n2 + 255) / 256, 256, 0, stream>>>((const float2*)f,
                                                   (const float2*)coll,
                                                   (const float2*)srct,
                                                   trans, (float2*)out, n2);
}